// Round 8
// baseline (447.938 us; speedup 1.0000x reference)
//
#include <hip/hip_runtime.h>
#include <hip/hip_bf16.h>
#include <math.h>

// ---------------------------------------------------------------------------
// 2-layer GCN on MI355X.
//   CSR build (hist -> wave-scan -> scatter)
//   xw1 = x @ W1    LDS MFMA GEMM, T14 prefetch, OUT = bf16 CHUNKED [8][N][32]
//   h1  = relu(sym-norm-agg(xw1) + b1)   XCD-chunked L2-resident gather
//   hw2 = h1 @ W2   LDS MFMA, OUT = bf16 CHUNKED [2][N][32]
//   logits = sym-norm-agg(hw2) + b2      XCD-chunked gather, f32
//   out = softmax(logits)
// ---------------------------------------------------------------------------

#define N_NODES 50000
#define N_EDGES 800000
#define D_IN    512
#define D_HID   256
#define D_OUT   64

#define CHUNK_ELEMS 1600000            // 50000*32 ushorts per feature-chunk

#define OFF_COUNTER 0
#define OFF_DEG     256
#define OFF_DINV    (OFF_DEG + 200704)
#define OFF_OFFS    (OFF_DINV + 200704)
#define OFF_CURSOR  (OFF_OFFS + 200704)
#define OFF_CSR     (OFF_CURSOR + 200704)
#define OFF_XW1     (OFF_CSR + 3200000)     // xw1c bf16 25.6MB; later hw2c 6.4MB + logits
#define OFF_LOGITS  (OFF_XW1 + 8000000)     // f32 [N][64] 12.8MB (inside dead xw1c span)
#define OFF_H1      (OFF_XW1 + 51200000)    // h1 bf16 row-major 25.6MB
#define OFF_BHT     OFF_H1                  // W1 hi/lo split (dead before agg1 writes h1)
#define OFF_BLT     (OFF_H1 + 524288)
#define OFF_W2T     (OFF_H1 + 25600000)     // W2T bf16 32KB
// total ~105 MB

typedef __attribute__((ext_vector_type(8))) short bf16x8;
typedef __attribute__((ext_vector_type(4))) float f32x4;

__device__ __forceinline__ unsigned int f2bf(float v) {
    unsigned int u = __float_as_uint(v);
    return (u + 0x7FFFu + ((u >> 16) & 1u)) >> 16;
}
__device__ __forceinline__ float bflo(unsigned int v) { return __uint_as_float(v << 16); }
__device__ __forceinline__ float bfhi(unsigned int v) { return __uint_as_float(v & 0xFFFF0000u); }

// ---------------- CSR build ----------------

__global__ void k_hist(const int* __restrict__ dst, int* __restrict__ deg) {
    int e = blockIdx.x * 256 + threadIdx.x;
    if (e < N_EDGES) atomicAdd(&deg[dst[e]], 1);
}

__global__ void k_scan(const int* __restrict__ deg, float* __restrict__ dinv,
                       int* __restrict__ offs, int* __restrict__ cursor,
                       int* __restrict__ counter) {
    int lane = threadIdx.x;           // block = 64
    int i = blockIdx.x * 64 + lane;
    int v = (i < N_NODES) ? deg[i] : 0;
    if (i < N_NODES) dinv[i] = rsqrtf((float)(v + 1));   // +1 self loop
    int incl = v;
    #pragma unroll
    for (int d = 1; d < 64; d <<= 1) {
        int t = __shfl_up(incl, d);
        if (lane >= d) incl += t;
    }
    int total = __shfl(incl, 63);
    int base = 0;
    if (lane == 63) base = atomicAdd(counter, total);
    base = __shfl(base, 63);
    int off = base + incl - v;
    if (i < N_NODES) { offs[i] = off; cursor[i] = off; }
}

__global__ void k_scatter(const int* __restrict__ src, const int* __restrict__ dst,
                          int* __restrict__ cursor, int* __restrict__ csr) {
    int e = blockIdx.x * 256 + threadIdx.x;
    if (e < N_EDGES) {
        int d = dst[e];
        int slot = atomicAdd(&cursor[d], 1);
        csr[slot] = src[e];
    }
}

// ---------------- weight prep (merged): W1 split+T, W2 bf16+T ----------------
__global__ void k_prep(const float* __restrict__ W1, const float* __restrict__ W2,
                       unsigned short* __restrict__ hT, unsigned short* __restrict__ lT,
                       unsigned short* __restrict__ W2T) {
    int b = blockIdx.x;
    if (b < 512) {                        // W1[512][256] -> hT/lT [256][512]
        int idx = b * 256 + threadIdx.x;
        int k = idx >> 8, n = idx & 255;
        float v = W1[idx];
        unsigned int h = f2bf(v);
        float hf = __uint_as_float(h << 16);
        unsigned int l = f2bf(v - hf);
        hT[n * 512 + k] = (unsigned short)h;
        lT[n * 512 + k] = (unsigned short)l;
    } else {                              // W2[256][64] -> W2T[64][256]
        int idx = (b - 512) * 256 + threadIdx.x;
        int k = idx >> 6, n = idx & 63;
        W2T[n * 256 + k] = (unsigned short)f2bf(W2[idx]);
    }
}

// ---------------- GEMM1: xw1c[8][N][32](bf16) = bf16(A) @ (W1h+W1l) -----------
// 128x128 tile, 4 waves, BK=32, T14 prefetch (unchanged structure from r7).
__global__ __launch_bounds__(256) void k_gemm1_mfma(const float* __restrict__ A,
        const unsigned short* __restrict__ BhT, const unsigned short* __restrict__ BlT,
        unsigned short* __restrict__ Cc, int M) {
    __shared__ unsigned short Ab[128][40];
    __shared__ unsigned short Bh[128][40];   // [col][k]
    __shared__ unsigned short Bl[128][40];

    const int tid = threadIdx.x;
    const int lane = tid & 63;
    const int wave = tid >> 6;
    const int wrow = (wave >> 1) * 64;
    const int wcol = (wave & 1) * 64;
    const int rowBase = blockIdx.x * 128;
    const int colBase = blockIdx.y * 128;

    const int arow = tid >> 1;
    const int ahalf = tid & 1;
    const int grow = rowBase + arow;
    const bool aval = (grow < M);
    const float* aptr = A + (size_t)grow * D_IN + ahalf * 16;
    const unsigned short* bhptr = BhT + (size_t)(colBase + arow) * D_IN + ahalf * 16;
    const unsigned short* blptr = BlT + (size_t)(colBase + arow) * D_IN + ahalf * 16;

    f32x4 acc[4][4];
    #pragma unroll
    for (int i = 0; i < 4; ++i)
        #pragma unroll
        for (int j = 0; j < 4; ++j) acc[i][j] = (f32x4)0.f;

    const int l15 = lane & 15;
    const int g = lane >> 4;

    float4 av0, av1, av2, av3;
    uint4 bh0, bh1, bl0, bl1;

    auto LOADS = [&](int k0) {
        av0 = av1 = av2 = av3 = make_float4(0.f, 0.f, 0.f, 0.f);
        if (aval) {
            av0 = *(const float4*)(aptr + k0);
            av1 = *(const float4*)(aptr + k0 + 4);
            av2 = *(const float4*)(aptr + k0 + 8);
            av3 = *(const float4*)(aptr + k0 + 12);
        }
        bh0 = *(const uint4*)(bhptr + k0);
        bh1 = *(const uint4*)(bhptr + k0 + 8);
        bl0 = *(const uint4*)(blptr + k0);
        bl1 = *(const uint4*)(blptr + k0 + 8);
    };
    auto STORE = [&]() {
        float vv[16] = {av0.x,av0.y,av0.z,av0.w, av1.x,av1.y,av1.z,av1.w,
                        av2.x,av2.y,av2.z,av2.w, av3.x,av3.y,av3.z,av3.w};
        unsigned int p[8];
        #pragma unroll
        for (int e = 0; e < 8; ++e)
            p[e] = f2bf(vv[2*e]) | (f2bf(vv[2*e+1]) << 16);
        *(uint4*)&Ab[arow][ahalf*16]     = make_uint4(p[0], p[1], p[2], p[3]);
        *(uint4*)&Ab[arow][ahalf*16 + 8] = make_uint4(p[4], p[5], p[6], p[7]);
        *(uint4*)&Bh[arow][ahalf*16]     = bh0;
        *(uint4*)&Bh[arow][ahalf*16 + 8] = bh1;
        *(uint4*)&Bl[arow][ahalf*16]     = bl0;
        *(uint4*)&Bl[arow][ahalf*16 + 8] = bl1;
    };

    LOADS(0);
    STORE();
    __syncthreads();

    for (int k0 = 0; k0 < D_IN; k0 += 32) {
        const int kn = k0 + 32;
        if (kn < D_IN) LOADS(kn);

        bf16x8 bhf[4], blf[4];
        #pragma unroll
        for (int j = 0; j < 4; ++j) {
            bhf[j] = *(const bf16x8*)&Bh[wcol + j*16 + l15][g*8];
            blf[j] = *(const bf16x8*)&Bl[wcol + j*16 + l15][g*8];
        }
        #pragma unroll
        for (int i = 0; i < 4; ++i) {
            bf16x8 abf = *(const bf16x8*)&Ab[wrow + i*16 + l15][g*8];
            #pragma unroll
            for (int j = 0; j < 4; ++j) {
                acc[i][j] = __builtin_amdgcn_mfma_f32_16x16x32_bf16(abf, bhf[j], acc[i][j], 0, 0, 0);
                acc[i][j] = __builtin_amdgcn_mfma_f32_16x16x32_bf16(abf, blf[j], acc[i][j], 0, 0, 0);
            }
        }
        __syncthreads();
        if (kn < D_IN) {
            STORE();
            __syncthreads();
        }
    }

    // epilogue -> CHUNKED bf16: feature col -> chunk col>>5, within-chunk col&31
    const int crow0 = rowBase + wrow + (lane >> 4) * 4;
    const int ccol = colBase + wcol + l15;
    #pragma unroll
    for (int i = 0; i < 4; ++i) {
        #pragma unroll
        for (int j = 0; j < 4; ++j) {
            int col = ccol + j * 16;
            size_t cbase = (size_t)(col >> 5) * CHUNK_ELEMS + (col & 31);
            #pragma unroll
            for (int r = 0; r < 4; ++r) {
                int m = crow0 + i * 16 + r;
                if (m < M) Cc[cbase + (size_t)m * 32] = (unsigned short)f2bf(acc[i][j][r]);
            }
        }
    }
}

// ---------------- agg1 chunked: h1[n][256] = relu(agg(xw1c) + b1) --------------
// chunk = bid%8 pinned to XCD (dispatch round-robin heuristic). Table slice
// 3.2MB -> L2-resident. 16 lanes/node x 2 feats (uint), 4 nodes/wave.
__global__ __launch_bounds__(256) void k_agg1c(const unsigned short* __restrict__ xwc,
                                               const float* __restrict__ dinv,
                                               const int* __restrict__ offs,
                                               const int* __restrict__ degin,
                                               const int* __restrict__ csr,
                                               const float* __restrict__ b1,
                                               unsigned int* __restrict__ h1u) {
    const int bid = blockIdx.x;
    const int chunk = bid & 7;
    const int nodeblk = bid >> 3;          // 0..3124
    const int tid = threadIdx.x;
    const int f2 = tid & 15;               // feature pair index
    const int nl = tid >> 4;               // 0..15
    const int n = nodeblk * 16 + nl;       // < 50000 exactly

    const unsigned int* tab = (const unsigned int*)(xwc + (size_t)chunk * CHUNK_ELEMS);

    const float dn = dinv[n];
    const int start = offs[n];
    const int cnt = degin[n];

    unsigned int sv = tab[n * 16 + f2];
    float a0 = dn * bflo(sv);
    float a1 = dn * bfhi(sv);

    int i = 0;
    for (; i + 2 <= cnt; i += 2) {
        int s0 = csr[start + i];
        int s1 = csr[start + i + 1];
        float w0 = dinv[s0], w1 = dinv[s1];
        unsigned int v0 = tab[s0 * 16 + f2];
        unsigned int v1 = tab[s1 * 16 + f2];
        a0 = fmaf(w0, bflo(v0), a0);
        a1 = fmaf(w0, bfhi(v0), a1);
        a0 = fmaf(w1, bflo(v1), a0);
        a1 = fmaf(w1, bfhi(v1), a1);
    }
    if (i < cnt) {
        int s0 = csr[start + i];
        float w0 = dinv[s0];
        unsigned int v0 = tab[s0 * 16 + f2];
        a0 = fmaf(w0, bflo(v0), a0);
        a1 = fmaf(w0, bfhi(v0), a1);
    }
    int fb = chunk * 32 + 2 * f2;
    float o0 = fmaxf(fmaf(a0, dn, b1[fb]), 0.f);
    float o1 = fmaxf(fmaf(a1, dn, b1[fb + 1]), 0.f);
    h1u[(size_t)n * 128 + chunk * 16 + f2] = f2bf(o0) | (f2bf(o1) << 16);
}

// ---------------- GEMM2: hw2c[2][N][32](bf16) = h1 @ W2 -----------------------
__global__ __launch_bounds__(256) void k_gemm2_mfma(const unsigned short* __restrict__ A,
        const unsigned short* __restrict__ BT, unsigned short* __restrict__ Cc, int M) {
    __shared__ unsigned short As[128][40];
    __shared__ unsigned short Bs[64][260];   // [col][k]

    const int tid = threadIdx.x;
    const int lane = tid & 63;
    const int wave = tid >> 6;
    const int wrow = wave * 32;
    const int rowBase = blockIdx.x * 128;

    {
        const int col = tid >> 2;
        const int kq = (tid & 3) * 64;
        const unsigned short* p = BT + (size_t)col * 256 + kq;
        #pragma unroll
        for (int u = 0; u < 8; ++u) {
            uint4 v = *(const uint4*)(p + u * 8);
            *(uint4*)&Bs[col][kq + u * 8] = v;
        }
    }

    const int arow = tid >> 1;
    const int ahalf = tid & 1;
    const int grow = rowBase + arow;
    const bool aval = (grow < M);
    const unsigned short* aptr = A + (size_t)grow * D_HID + ahalf * 16;

    f32x4 acc[2][4];
    #pragma unroll
    for (int i = 0; i < 2; ++i)
        #pragma unroll
        for (int j = 0; j < 4; ++j) acc[i][j] = (f32x4)0.f;

    const int l15 = lane & 15;
    const int g = lane >> 4;

    uint4 a0, a1;
    auto LOADS = [&](int k0) {
        a0 = a1 = make_uint4(0, 0, 0, 0);
        if (aval) {
            a0 = *(const uint4*)(aptr + k0);
            a1 = *(const uint4*)(aptr + k0 + 8);
        }
    };

    LOADS(0);
    *(uint4*)&As[arow][ahalf*16]     = a0;
    *(uint4*)&As[arow][ahalf*16 + 8] = a1;
    __syncthreads();

    for (int k0 = 0; k0 < D_HID; k0 += 32) {
        const int kn = k0 + 32;
        if (kn < D_HID) LOADS(kn);

        bf16x8 bf[4];
        #pragma unroll
        for (int j = 0; j < 4; ++j)
            bf[j] = *(const bf16x8*)&Bs[j*16 + l15][k0 + g*8];
        #pragma unroll
        for (int i = 0; i < 2; ++i) {
            bf16x8 af = *(const bf16x8*)&As[wrow + i*16 + l15][g*8];
            #pragma unroll
            for (int j = 0; j < 4; ++j)
                acc[i][j] = __builtin_amdgcn_mfma_f32_16x16x32_bf16(af, bf[j], acc[i][j], 0, 0, 0);
        }
        __syncthreads();
        if (kn < D_HID) {
            *(uint4*)&As[arow][ahalf*16]     = a0;
            *(uint4*)&As[arow][ahalf*16 + 8] = a1;
            __syncthreads();
        }
    }

    const int crow0 = rowBase + wrow + (lane >> 4) * 4;
    #pragma unroll
    for (int i = 0; i < 2; ++i) {
        #pragma unroll
        for (int j = 0; j < 4; ++j) {
            int col = l15 + j * 16;
            size_t cbase = (size_t)(col >> 5) * CHUNK_ELEMS + (col & 31);
            #pragma unroll
            for (int r = 0; r < 4; ++r) {
                int m = crow0 + i * 16 + r;
                if (m < M) Cc[cbase + (size_t)m * 32] = (unsigned short)f2bf(acc[i][j][r]);
            }
        }
    }
}

// ---------------- agg2 chunked -> f32 logits ----------------------------------
// 2 chunks of 32 feats; chunk = (bid%8)>>2 so 4 XCDs serve each 3.2MB slice.
__global__ __launch_bounds__(256) void k_agg2c(const unsigned short* __restrict__ hwc,
                                               const float* __restrict__ dinv,
                                               const int* __restrict__ offs,
                                               const int* __restrict__ degin,
                                               const int* __restrict__ csr,
                                               const float* __restrict__ b2,
                                               float* __restrict__ logits) {
    const int bid = blockIdx.x;            // grid = 8*782 = 6256
    const int xcd = bid & 7;
    const int chunk = xcd >> 2;
    const int g = bid >> 3;                // 0..781
    const int tid = threadIdx.x;
    const int f2 = tid & 15;
    const int nl = tid >> 4;
    const int nodeblk = (xcd & 3) * 782 + g;
    const int n = nodeblk * 16 + nl;
    if (n >= N_NODES) return;

    const unsigned int* tab = (const unsigned int*)(hwc + (size_t)chunk * CHUNK_ELEMS);

    const float dn = dinv[n];
    const int start = offs[n];
    const int cnt = degin[n];

    unsigned int sv = tab[n * 16 + f2];
    float a0 = dn * bflo(sv);
    float a1 = dn * bfhi(sv);

    int i = 0;
    for (; i + 2 <= cnt; i += 2) {
        int s0 = csr[start + i];
        int s1 = csr[start + i + 1];
        float w0 = dinv[s0], w1 = dinv[s1];
        unsigned int v0 = tab[s0 * 16 + f2];
        unsigned int v1 = tab[s1 * 16 + f2];
        a0 = fmaf(w0, bflo(v0), a0);
        a1 = fmaf(w0, bfhi(v0), a1);
        a0 = fmaf(w1, bflo(v1), a0);
        a1 = fmaf(w1, bfhi(v1), a1);
    }
    if (i < cnt) {
        int s0 = csr[start + i];
        float w0 = dinv[s0];
        unsigned int v0 = tab[s0 * 16 + f2];
        a0 = fmaf(w0, bflo(v0), a0);
        a1 = fmaf(w0, bfhi(v0), a1);
    }
    int fb = chunk * 32 + 2 * f2;
    float2 lg = make_float2(fmaf(a0, dn, b2[fb]), fmaf(a1, dn, b2[fb + 1]));
    *(float2*)&logits[(size_t)n * 64 + fb] = lg;
}

// ---------------- softmax over 64 feats: wave per node ------------------------
__global__ __launch_bounds__(256) void k_softmax(const float* __restrict__ logits,
                                                 float* __restrict__ out) {
    const int wave = threadIdx.x >> 6;
    const int lane = threadIdx.x & 63;
    const int n = blockIdx.x * 4 + wave;   // 50000 = 12500*4
    float v = logits[(size_t)n * 64 + lane];
    float m = v;
    #pragma unroll
    for (int d = 32; d > 0; d >>= 1) m = fmaxf(m, __shfl_xor(m, d));
    float e = expf(v - m);
    float s = e;
    #pragma unroll
    for (int d = 32; d > 0; d >>= 1) s += __shfl_xor(s, d);
    out[(size_t)n * 64 + lane] = e / s;
}

// ---------------- launch ----------------

extern "C" void kernel_launch(void* const* d_in, const int* in_sizes, int n_in,
                              void* d_out, int out_size, void* d_ws, size_t ws_size,
                              hipStream_t stream) {
    const float* x  = (const float*)d_in[0];
    const int*   ei = (const int*)d_in[1];
    const float* W1 = (const float*)d_in[2];
    const float* b1 = (const float*)d_in[3];
    const float* W2 = (const float*)d_in[4];
    const float* b2 = (const float*)d_in[5];
    float* out = (float*)d_out;

    const int* src = ei;
    const int* dst = ei + N_EDGES;

    char* ws = (char*)d_ws;
    int*   counter = (int*)(ws + OFF_COUNTER);
    int*   deg     = (int*)(ws + OFF_DEG);
    float* dinv    = (float*)(ws + OFF_DINV);
    int*   offs    = (int*)(ws + OFF_OFFS);
    int*   cursor  = (int*)(ws + OFF_CURSOR);
    int*   csr     = (int*)(ws + OFF_CSR);
    unsigned short* xw1c = (unsigned short*)(ws + OFF_XW1);   // bf16 [8][N][32]
    unsigned short* hw2c = (unsigned short*)(ws + OFF_XW1);   // bf16 [2][N][32] (xw1c dead)
    float* logits  = (float*)(ws + OFF_LOGITS);               // f32 [N][64]
    unsigned int* h1u = (unsigned int*)(ws + OFF_H1);         // bf16 [N][256] as uints
    unsigned short* h1b = (unsigned short*)(ws + OFF_H1);
    unsigned short* BhT = (unsigned short*)(ws + OFF_BHT);
    unsigned short* BlT = (unsigned short*)(ws + OFF_BLT);
    unsigned short* W2T = (unsigned short*)(ws + OFF_W2T);

    hipMemsetAsync(ws, 0, OFF_DEG + N_NODES * sizeof(int), stream);

    k_hist<<<(N_EDGES + 255) / 256, 256, 0, stream>>>(dst, deg);
    k_scan<<<(N_NODES + 63) / 64, 64, 0, stream>>>(deg, dinv, offs, cursor, counter);
    k_scatter<<<(N_EDGES + 255) / 256, 256, 0, stream>>>(src, dst, cursor, csr);

    k_prep<<<576, 256, 0, stream>>>(W1, W2, BhT, BlT, W2T);

    k_gemm1_mfma<<<dim3((N_NODES + 127) / 128, D_HID / 128), 256, 0, stream>>>(x, BhT, BlT, xw1c, N_NODES);
    k_agg1c<<<(N_NODES / 16) * 8, 256, 0, stream>>>(xw1c, dinv, offs, deg, csr, b1, h1u);
    k_gemm2_mfma<<<(N_NODES + 127) / 128, 256, 0, stream>>>(h1b, W2T, hw2c, N_NODES);
    k_agg2c<<<8 * 782, 256, 0, stream>>>(hw2c, dinv, offs, deg, csr, b2, logits);
    k_softmax<<<N_NODES / 4, 256, 0, stream>>>(logits, out);
}